// Round 9
// baseline (168.648 us; speedup 1.0000x reference)
//
#include <hip/hip_runtime.h>

// grid [2,160,160,160,3] fp32; interior outputs (i,j,k) in 2..157 per axis.
//
// R9: R8's single-wave barrier-free march, x2 independent tiles per wave.
// Every pipe was <=25% busy in R6-R8 and neither occupancy (R1/R5) nor
// barrier removal (R8) moved dur -> the per-step dependency chain
// (vmcnt -> ds_write -> ds_read -> lgkm -> DPP/FMA) is the wall and wave-TLP
// isn't covering it. R9 interleaves TWO fully independent z-tiles (zt, zt+5)
// in ONE wave: separate LDS rings, staging banks, x-pipelines; while tile A
// waits on its counted lgkm/vmcnt, tile B's VALU issues (in-wave ILP, which
// the compiler schedules reliably; does not depend on the CU scheduler).
// Per tile (verified R8 logic): wave = 16 y-rows (DPP rows) x 4 z-quads,
// 3-slice LDS ring, 2-deep register staging, y-stencil via DPP row_shr/shl,
// x-terms via parity-bank register pipeline. No __syncthreads anywhere
// (intra-wave DS ordering). d-loop kept rolled (I$: ~4 step bodies).
#define OY 480                    // floats per y-row (160 z * 3 comps)
#define OX 76800                  // floats per x-slice
#define SB 12288000               // floats per batch
#define RST 60                    // LDS row stride (floats)
#define SLC 960                   // floats per slice (16 rows * 60)
#define IT 12                     // output slices (x) per wave; 13 segs
#define NSEG 13
#define NBLK 1690                 // 2(bb) * 13(jt) * 5(ztp) * 13(is)
#define INV_SIZE (1.0f/22778496.0f)  // 2*156^3*3

#define ROW_SHL1 0x101
#define ROW_SHL2 0x102
#define ROW_SHR1 0x111
#define ROW_SHR2 0x112

template<int CTRL>
__device__ __forceinline__ float dppf(float x){
    return __int_as_float(__builtin_amdgcn_update_dpp(
        0, __float_as_int(x), CTRL, 0xF, 0xF, true));
}

__device__ __forceinline__ float4 ld4p(const float* p){ return *reinterpret_cast<const float4*>(p); }
__device__ __forceinline__ void st4p(float* p, float4 v){ *reinterpret_cast<float4*>(p) = v; }

// One x-step of one tile; s runtime (wave-uniform branches). SBc holds slice
// s+1 (written to ring); SBn receives slice s+2. DPP sits under the per-row
// uniform qactT only; per-lane vr gates accumulation exclusively.
#define STEPT(s, V0a, V0b, DP, SBc, SBn, GT, LT, ojT, qactT) { \
    if ((s) <= 13) { \
        const float* bp = GT + (size_t)((s)+2)*OX; \
        SBn[0]=ld4p(bp+gof0); SBn[1]=ld4p(bp+gof1); SBn[2]=ld4p(bp+gof2); \
        if (wv3) SBn[3]=ld4p(bp+gof3); \
    } \
    if (qactT) { \
        const float* Lr = LT + ((s)%3)*SLC + ojT; \
        float x[24]; \
        { float4 y0=ld4p(Lr),y1=ld4p(Lr+4),y2=ld4p(Lr+8),y3=ld4p(Lr+12),y4=ld4p(Lr+16),y5=ld4p(Lr+20); \
          x[0]=y0.x;x[1]=y0.y;x[2]=y0.z;x[3]=y0.w; x[4]=y1.x;x[5]=y1.y;x[6]=y1.z;x[7]=y1.w; \
          x[8]=y2.x;x[9]=y2.y;x[10]=y2.z;x[11]=y2.w; x[12]=y3.x;x[13]=y3.y;x[14]=y3.z;x[15]=y3.w; \
          x[16]=y4.x;x[17]=y4.y;x[18]=y4.z;x[19]=y4.w; x[20]=y5.x;x[21]=y5.y;x[22]=y5.z;x[23]=y5.w; } \
        float dz0[4],dz1[4],dz2[4],dy0[4],dy1[4],v0c[4]; \
        _Pragma("unroll") for (int v=0; v<4; ++v) { \
            v0c[v] = x[3*v+6]; \
            dz0[v] = x[3*v+9]-x[3*v+3]; dz1[v]=x[3*v+10]-x[3*v+4]; dz2[v]=x[3*v+11]-x[3*v+5]; \
            dy0[v] = dppf<ROW_SHR1>(x[3*v+6]) - dppf<ROW_SHL1>(x[3*v+6]); \
            dy1[v] = dppf<ROW_SHR1>(x[3*v+7]) - dppf<ROW_SHL1>(x[3*v+7]); \
        } \
        if ((s) >= 2 && (s) <= 13) { \
            _Pragma("unroll") for (int v=0; v<4; ++v) { \
                float c0=x[3*v+6], c1=x[3*v+7]; \
                float hy0 = dppf<ROW_SHR2>(c0) - 2.f*c0 + dppf<ROW_SHL2>(c0); \
                float hy1 = dppf<ROW_SHR2>(c1) - 2.f*c1 + dppf<ROW_SHL2>(c1); \
                float yz0 = dppf<ROW_SHR1>(dz0[v]) - dppf<ROW_SHL1>(dz0[v]); \
                float yz1 = dppf<ROW_SHR1>(dz1[v]) - dppf<ROW_SHL1>(dz1[v]); \
                float yz2 = dppf<ROW_SHR1>(dz2[v]) - dppf<ROW_SHL1>(dz2[v]); \
                if (vr) { \
                    float zz0 = x[3*v+12]-2.f*x[3*v+6]+x[3*v]; \
                    float zz1 = x[3*v+13]-2.f*x[3*v+7]+x[3*v+1]; \
                    float zz2 = x[3*v+14]-2.f*x[3*v+8]+x[3*v+2]; \
                    cls2=fmaf(zz0,zz0,cls2); cls2=fmaf(zz1,zz1,cls2); cls1=fmaf(zz2,zz2,cls1); \
                    cls2=fmaf(hy0,hy0,cls2); cls1=fmaf(hy1,hy1,cls1); \
                    cls4=fmaf(yz0,yz0,cls4); cls3=fmaf(yz1,yz1,cls3); cls1=fmaf(yz2,yz2,cls1); \
                } \
            } \
        } \
        _Pragma("unroll") for (int v=0; v<4; ++v) { \
            if (vr && (s) >= 3 && (s) <= 14) { float h; \
                h=dy0[v]-DP[0][v]; cls3=fmaf(h,h,cls3); \
                h=dy1[v]-DP[1][v]; cls1=fmaf(h,h,cls1); \
                h=dz0[v]-DP[2][v]; cls3=fmaf(h,h,cls3); \
                h=dz1[v]-DP[3][v]; cls2=fmaf(h,h,cls2); \
                h=dz2[v]-DP[4][v]; cls1=fmaf(h,h,cls1); \
            } \
            DP[0][v]=dy0[v]; DP[1][v]=dy1[v]; DP[2][v]=dz0[v]; DP[3][v]=dz1[v]; DP[4][v]=dz2[v]; \
            if (vr && (s) >= 4) { float h = v0c[v]-2.f*V0a[v]+V0b[v]; cls1=fmaf(h,h,cls1); } \
            V0b[v]=V0a[v]; V0a[v]=v0c[v]; \
        } \
    } \
    if ((s) <= 14) { \
        float* Lw = LT + (((s)+1)%3)*SLC; \
        st4p(Lw+lof0, SBc[0]); st4p(Lw+lof1, SBc[1]); st4p(Lw+lof2, SBc[2]); \
        if (wv3) st4p(Lw+lof3, SBc[3]); \
    } \
}

__global__ __launch_bounds__(64)
void be_partials(const float* __restrict__ g, float* __restrict__ partial) {
    __shared__ float lds[6*SLC];   // 2 tiles x 3-slice ring, 22.5 KB

    const int tid = threadIdx.x;
    const int bid = blockIdx.x;
    const int is = bid % NSEG;
    int r1 = bid / NSEG;
    const int ztp = r1 % 5; r1 /= 5;
    const int jt = r1 % 13;
    const int bb = r1 / 13;

    const int ztA = ztp;           // 0..4 (always full 4 quads)
    const int ztB = ztp + 5;       // 5..9 (ztB=9 is the z-edge tile)
    const int j0 = 2 + jt*12;      // output rows j0..j0+11 (stage j0-2..j0+13)
    const int i0 = 2 + is*IT;      // output slices i0..i0+11
    const int wbA = 48*ztA;
    const int wbB = (ztB < 9) ? 48*ztB : 420;
    const float* __restrict__ GA =
        g + (size_t)bb*SB + (size_t)(j0-2)*OY + wbA + (size_t)(i0-2)*OX;
    const float* __restrict__ GB =
        g + (size_t)bb*SB + (size_t)(j0-2)*OY + wbB + (size_t)(i0-2)*OX;
    float* __restrict__ ldsA = lds;
    float* __restrict__ ldsB = lds + 3*SLC;

    // ---- staging offsets (shared by both tiles): 240 f4 = 16 rows x 15 ----
    int gof0,gof1,gof2,gof3,lof0,lof1,lof2,lof3;
    { int f,row,pos;
      f=tid;     row=f/15; pos=f-15*row; gof0=row*OY+4*pos; lof0=row*RST+4*pos;
      f=tid+64;  row=f/15; pos=f-15*row; gof1=row*OY+4*pos; lof1=row*RST+4*pos;
      f=tid+128; row=f/15; pos=f-15*row; gof2=row*OY+4*pos; lof2=row*RST+4*pos;
      f=tid+192; row=f/15; pos=f-15*row; gof3=row*OY+4*pos; lof3=row*RST+4*pos; }
    const bool wv3 = tid < 48;
    if (!wv3) { gof3 = gof0; lof3 = lof0; }

    // ---- compute mapping: r = y-row (DPP row pos), Q = z-quad ----
    const int r = tid & 15;
    const int Q = tid >> 4;                    // 0..3, uniform per DPP row
    const bool qactB = (ztB == 9) ? (Q < 3) : true;   // zt=9: out z 146..157
    const bool vr = (r >= 2) && (r <= 13);     // output rows
    const int ojA = r*RST + 12*Q;
    const int ojB = r*RST + 12*Q + ((ztB == 9) ? 12 : 0);

    // per-tile x-pipeline state (parity banks E=even step, O=odd step)
    float4 sA0[4], sA1[4], sB0[4], sB1[4];
    float vAe0[4],vAe1[4],vAo0[4],vAo1[4], vBe0[4],vBe1[4],vBo0[4],vBo1[4];
    float dpAe[5][4], dpAo[5][4], dpBe[5][4], dpBo[5][4];
    #pragma unroll
    for (int v=0; v<4; ++v) {
        vAe0[v]=vAe1[v]=vAo0[v]=vAo1[v]=0.f;
        vBe0[v]=vBe1[v]=vBo0[v]=vBo1[v]=0.f;
        #pragma unroll
        for (int q=0; q<5; ++q) {
            dpAe[q][v]=dpAo[q][v]=0.f; dpBe[q][v]=dpBo[q][v]=0.f;
        }
    }
    float cls1=0.f, cls2=0.f, cls3=0.f, cls4=0.f;

    // prologue: per tile, slice 0 -> ring[0]; slice 1 -> odd bank
    { float4 a0=ld4p(GA+gof0), a1=ld4p(GA+gof1), a2=ld4p(GA+gof2);
      st4p(ldsA+lof0,a0); st4p(ldsA+lof1,a1); st4p(ldsA+lof2,a2);
      if (wv3) { float4 a3=ld4p(GA+gof3); st4p(ldsA+lof3,a3); } }
    { float4 a0=ld4p(GB+gof0), a1=ld4p(GB+gof1), a2=ld4p(GB+gof2);
      st4p(ldsB+lof0,a0); st4p(ldsB+lof1,a1); st4p(ldsB+lof2,a2);
      if (wv3) { float4 a3=ld4p(GB+gof3); st4p(ldsB+lof3,a3); } }
    { const float* bp = GA + OX;
      sA1[0]=ld4p(bp+gof0); sA1[1]=ld4p(bp+gof1); sA1[2]=ld4p(bp+gof2);
      if (wv3) sA1[3]=ld4p(bp+gof3); }
    { const float* bp = GB + OX;
      sB1[0]=ld4p(bp+gof0); sB1[1]=ld4p(bp+gof1); sB1[2]=ld4p(bp+gof2);
      if (wv3) sB1[3]=ld4p(bp+gof3); }

    #pragma unroll 1
    for (int d = 0; d < 8; ++d) {
        const int s0 = 2*d, s1 = 2*d + 1;
        STEPT(s0, vAe0,vAe1,dpAe, sA1,sA0, GA, ldsA, ojA, true)
        STEPT(s0, vBe0,vBe1,dpBe, sB1,sB0, GB, ldsB, ojB, qactB)
        STEPT(s1, vAo0,vAo1,dpAo, sA0,sA1, GA, ldsA, ojA, true)
        STEPT(s1, vBo0,vBo1,dpBo, sB0,sB1, GB, ldsB, ojB, qactB)
    }

    // fold weight classes (multiplicities 1,2,3,4; 0.0625 = (0.25)^2)
    float sv = fmaf(2.f, cls2, cls1);
    sv = fmaf(3.f, cls3, sv);
    sv = fmaf(4.f, cls4, sv);
    sv *= 0.0625f;

    #pragma unroll
    for (int off = 32; off > 0; off >>= 1) sv += __shfl_down(sv, off, 64);
    if (tid == 0) partial[bid] = sv;
}

__global__ __launch_bounds__(256)
void be_final(const float* __restrict__ partial, float* __restrict__ out) {
    float s = 0.0f;
    for (int i = threadIdx.x; i < NBLK; i += 256) s += partial[i];
    #pragma unroll
    for (int off = 32; off > 0; off >>= 1) s += __shfl_down(s, off, 64);
    __shared__ float ws[4];
    if ((threadIdx.x & 63) == 0) ws[threadIdx.x >> 6] = s;
    __syncthreads();
    if (threadIdx.x == 0)
        out[0] = ((ws[0] + ws[1]) + (ws[2] + ws[3])) * INV_SIZE;
}

extern "C" void kernel_launch(void* const* d_in, const int* in_sizes, int n_in,
                              void* d_out, int out_size, void* d_ws, size_t ws_size,
                              hipStream_t stream) {
    const float* grid = (const float*)d_in[0];
    float* out = (float*)d_out;
    float* partials = (float*)d_ws;    // 1690 floats

    be_partials<<<dim3(NBLK), dim3(64), 0, stream>>>(grid, partials);
    be_final<<<1, 256, 0, stream>>>(partials, out);
}

// Round 10
// 160.753 us; speedup vs baseline: 1.0491x; 1.0491x over previous
//
#include <hip/hip_runtime.h>

// grid [2,160,160,160,3] fp32; interior outputs (i,j,k) in 2..157 per axis.
//
// R10: R8's single-wave barrier-free DPP march + zero-VGPR deep prefetch via
// global_load_lds. Diagnosis across R1-R9: every pipe <30% busy and effective
// HBM read rate pinned at 1.3-2.4 TB/s (FETCH/dur) in every round -> the
// kernel never has enough bytes in flight (Little's law: ~5-8KB/wave).
// Register staging buys depth with VGPRs (spill cliff, R4); more waves buys
// it with LDS (residency cliff, R9). global_load_lds buys it for free:
//   - 5-slice LDS ring, 4KB/slice (1024 floats: 960 data + 64 pad), 20KB tot
//     -> 8 single-wave blocks/CU.
//   - step S: issue slice S+3 (4 x global_load_lds_dwordx4, lane-linear
//     dest = the layout m104 requires; RST=60 makes float_off = 4*f exactly),
//     then s_waitcnt vmcnt(12) -> slice S landed, 3 slices (11.5KB) stay in
//     flight per wave continuously (~92KB/CU).
//   - no ds_writes at all; no __syncthreads anywhere (intra-wave ordering).
// Compute body = R8's verified DPP y-stencil + parity-bank x-pipeline.
#define OY 480                    // floats per y-row (160 z * 3 comps)
#define OX 76800                  // floats per x-slice
#define SB 12288000               // floats per batch
#define RST 60                    // LDS row stride (floats): 16 rows * 60 = 960
#define SLC 1024                  // ring slice stride (floats): 960 + 64 pad
#define IT 12                     // output slices (x) per wave; 13 segs
#define NSEG 13
#define NBLK 3380                 // 2(bb) * 13(jt) * 10(zt) * 13(is)
#define INV_SIZE (1.0f/22778496.0f)  // 2*156^3*3

#define ROW_SHL1 0x101
#define ROW_SHL2 0x102
#define ROW_SHR1 0x111
#define ROW_SHR2 0x112

template<int CTRL>
__device__ __forceinline__ float dppf(float x){
    return __int_as_float(__builtin_amdgcn_update_dpp(
        0, __float_as_int(x), CTRL, 0xF, 0xF, true));
}

__device__ __forceinline__ float4 ld4p(const float* p){ return *reinterpret_cast<const float4*>(p); }

// global -> LDS direct staging, 16B per lane. LDS dest is wave-uniform base
// + lane*16 (HW rule, m104); global src is per-lane.
__device__ __forceinline__ void stage16(const float* gp, float* lp){
    __builtin_amdgcn_global_load_lds(
        (const __attribute__((address_space(1))) void*)gp,
        (__attribute__((address_space(3))) void*)lp,
        16, 0, 0);
}

#define WAITVM(n) asm volatile("s_waitcnt vmcnt(" #n ")" ::: "memory")

// One x-step, S and N (vmcnt target) are LITERAL tokens. Issues slice S+3
// into ring[(S+3)%5], waits slice S landed (vmcnt(N)), computes from
// ring[S%5]. DPP sits under wave-uniform qact; per-lane vr gates accumulation.
#define STEPX(S, N, V0a, V0b, DP) { \
    if ((S)+3 <= 15) { \
        const float* bp = Gs + (size_t)((S)+3)*OX; \
        float* Ld = lds + (((S)+3)%5)*SLC; \
        stage16(bp+goff0, Ld); \
        stage16(bp+goff1, Ld+256); \
        stage16(bp+goff2, Ld+512); \
        stage16(bp+goff3, Ld+768); \
    } \
    WAITVM(N); \
    if (qact) { \
        const float* Lr = lds + ((S)%5)*SLC + oj; \
        float x[24]; \
        { float4 y0=ld4p(Lr),y1=ld4p(Lr+4),y2=ld4p(Lr+8),y3=ld4p(Lr+12),y4=ld4p(Lr+16),y5=ld4p(Lr+20); \
          x[0]=y0.x;x[1]=y0.y;x[2]=y0.z;x[3]=y0.w; x[4]=y1.x;x[5]=y1.y;x[6]=y1.z;x[7]=y1.w; \
          x[8]=y2.x;x[9]=y2.y;x[10]=y2.z;x[11]=y2.w; x[12]=y3.x;x[13]=y3.y;x[14]=y3.z;x[15]=y3.w; \
          x[16]=y4.x;x[17]=y4.y;x[18]=y4.z;x[19]=y4.w; x[20]=y5.x;x[21]=y5.y;x[22]=y5.z;x[23]=y5.w; } \
        float dz0[4],dz1[4],dz2[4],dy0[4],dy1[4],v0c[4]; \
        _Pragma("unroll") for (int v=0; v<4; ++v) { \
            v0c[v] = x[3*v+6]; \
            dz0[v] = x[3*v+9]-x[3*v+3]; dz1[v]=x[3*v+10]-x[3*v+4]; dz2[v]=x[3*v+11]-x[3*v+5]; \
            dy0[v] = dppf<ROW_SHR1>(x[3*v+6]) - dppf<ROW_SHL1>(x[3*v+6]); \
            dy1[v] = dppf<ROW_SHR1>(x[3*v+7]) - dppf<ROW_SHL1>(x[3*v+7]); \
        } \
        if ((S) >= 2 && (S) <= 13) { \
            _Pragma("unroll") for (int v=0; v<4; ++v) { \
                float c0=x[3*v+6], c1=x[3*v+7]; \
                float hy0 = dppf<ROW_SHR2>(c0) - 2.f*c0 + dppf<ROW_SHL2>(c0); \
                float hy1 = dppf<ROW_SHR2>(c1) - 2.f*c1 + dppf<ROW_SHL2>(c1); \
                float yz0 = dppf<ROW_SHR1>(dz0[v]) - dppf<ROW_SHL1>(dz0[v]); \
                float yz1 = dppf<ROW_SHR1>(dz1[v]) - dppf<ROW_SHL1>(dz1[v]); \
                float yz2 = dppf<ROW_SHR1>(dz2[v]) - dppf<ROW_SHL1>(dz2[v]); \
                if (vr) { \
                    float zz0 = x[3*v+12]-2.f*x[3*v+6]+x[3*v]; \
                    float zz1 = x[3*v+13]-2.f*x[3*v+7]+x[3*v+1]; \
                    float zz2 = x[3*v+14]-2.f*x[3*v+8]+x[3*v+2]; \
                    cls2=fmaf(zz0,zz0,cls2); cls2=fmaf(zz1,zz1,cls2); cls1=fmaf(zz2,zz2,cls1); \
                    cls2=fmaf(hy0,hy0,cls2); cls1=fmaf(hy1,hy1,cls1); \
                    cls4=fmaf(yz0,yz0,cls4); cls3=fmaf(yz1,yz1,cls3); cls1=fmaf(yz2,yz2,cls1); \
                } \
            } \
        } \
        _Pragma("unroll") for (int v=0; v<4; ++v) { \
            if (vr && (S) >= 3 && (S) <= 14) { float h; \
                h=dy0[v]-DP[0][v]; cls3=fmaf(h,h,cls3); \
                h=dy1[v]-DP[1][v]; cls1=fmaf(h,h,cls1); \
                h=dz0[v]-DP[2][v]; cls3=fmaf(h,h,cls3); \
                h=dz1[v]-DP[3][v]; cls2=fmaf(h,h,cls2); \
                h=dz2[v]-DP[4][v]; cls1=fmaf(h,h,cls1); \
            } \
            DP[0][v]=dy0[v]; DP[1][v]=dy1[v]; DP[2][v]=dz0[v]; DP[3][v]=dz1[v]; DP[4][v]=dz2[v]; \
            if (vr && (S) >= 4) { float h = v0c[v]-2.f*V0a[v]+V0b[v]; cls1=fmaf(h,h,cls1); } \
            V0b[v]=V0a[v]; V0a[v]=v0c[v]; \
        } \
    } \
}

__global__ __launch_bounds__(64)
void be_partials(const float* __restrict__ g, float* __restrict__ partial) {
    __shared__ float lds[5*SLC];   // 20 KB ring, private to this single wave

    const int tid = threadIdx.x;
    const int bid = blockIdx.x;
    const int is = bid % NSEG;
    int r1 = bid / NSEG;
    const int zt = r1 % 10; r1 /= 10;
    const int jt = r1 % 13;
    const int bb = r1 / 13;

    const int j0 = 2 + jt*12;               // output rows j0..j0+11
    const int wb = (zt < 9) ? 48*zt : 420;  // window float base (60 floats/row)
    const int i0 = 2 + is*IT;               // output slices i0..i0+11
    const float* __restrict__ Gs =
        g + (size_t)bb*SB + (size_t)(j0-2)*OY + wb + (size_t)(i0-2)*OX;

    // ---- staging addresses: 4 chunks x 64 lanes; f = 64c+lane -> row=f/15,
    // pos=f%15 (15 f4 per 60-float row). LDS float offset is implicitly 4f
    // (lane-linear), which equals row*60+4*pos exactly. f>=240 lanes clamp
    // their global src; their LDS bytes land in the 64-float slice pad. ----
    int goff0, goff1, goff2, goff3;
    { int f, vp;
      f = tid;       vp = f;                 goff0 = (vp/15)*OY + 4*(vp%15);
      f = tid + 64;  vp = f;                 goff1 = (vp/15)*OY + 4*(vp%15);
      f = tid + 128; vp = f;                 goff2 = (vp/15)*OY + 4*(vp%15);
      f = tid + 192; vp = (f < 240) ? f : 239; goff3 = (vp/15)*OY + 4*(vp%15); }

    // ---- compute mapping: r = y-row (DPP row pos), Q = z-quad ----
    const int r = tid & 15;
    const int Q = tid >> 4;
    const int qmax = (zt == 9) ? 3 : 4;       // zt=9 covers out z 146..157
    const bool qact = Q < qmax;               // uniform per 16-lane DPP row
    const bool vr = (r >= 2) && (r <= 13);    // output rows
    const int oj = r*RST + 12*Q + ((zt == 9) ? 12 : 0);

    // x-pipeline state (parity banks A=even step, B=odd step)
    float v0A0[4],v0A1[4],v0B0[4],v0B1[4];
    float dpA[5][4], dpB[5][4];
    #pragma unroll
    for (int v=0; v<4; ++v) {
        v0A0[v]=v0A1[v]=v0B0[v]=v0B1[v]=0.f;
        #pragma unroll
        for (int q=0; q<5; ++q) { dpA[q][v]=0.f; dpB[q][v]=0.f; }
    }
    float cls1=0.f, cls2=0.f, cls3=0.f, cls4=0.f;

    // prologue: issue slices 0,1,2 into ring[0..2] (12 loads in flight)
    #pragma unroll
    for (int sl = 0; sl < 3; ++sl) {
        const float* bp = Gs + (size_t)sl*OX;
        float* Ld = lds + sl*SLC;
        stage16(bp+goff0, Ld);
        stage16(bp+goff1, Ld+256);
        stage16(bp+goff2, Ld+512);
        stage16(bp+goff3, Ld+768);
    }

    STEPX( 0, 12, v0A0,v0A1,dpA)
    STEPX( 1, 12, v0B0,v0B1,dpB)
    STEPX( 2, 12, v0A0,v0A1,dpA)
    STEPX( 3, 12, v0B0,v0B1,dpB)
    STEPX( 4, 12, v0A0,v0A1,dpA)
    STEPX( 5, 12, v0B0,v0B1,dpB)
    STEPX( 6, 12, v0A0,v0A1,dpA)
    STEPX( 7, 12, v0B0,v0B1,dpB)
    STEPX( 8, 12, v0A0,v0A1,dpA)
    STEPX( 9, 12, v0B0,v0B1,dpB)
    STEPX(10, 12, v0A0,v0A1,dpA)
    STEPX(11, 12, v0B0,v0B1,dpB)
    STEPX(12, 12, v0A0,v0A1,dpA)
    STEPX(13,  8, v0B0,v0B1,dpB)
    STEPX(14,  4, v0A0,v0A1,dpA)
    STEPX(15,  0, v0B0,v0B1,dpB)

    // fold weight classes (multiplicities 1,2,3,4; 0.0625 = (0.25)^2)
    float sv = fmaf(2.f, cls2, cls1);
    sv = fmaf(3.f, cls3, sv);
    sv = fmaf(4.f, cls4, sv);
    sv *= 0.0625f;

    #pragma unroll
    for (int off = 32; off > 0; off >>= 1) sv += __shfl_down(sv, off, 64);
    if (tid == 0) partial[bid] = sv;
}

__global__ __launch_bounds__(256)
void be_final(const float* __restrict__ partial, float* __restrict__ out) {
    float s = 0.0f;
    for (int i = threadIdx.x; i < NBLK; i += 256) s += partial[i];
    #pragma unroll
    for (int off = 32; off > 0; off >>= 1) s += __shfl_down(s, off, 64);
    __shared__ float ws[4];
    if ((threadIdx.x & 63) == 0) ws[threadIdx.x >> 6] = s;
    __syncthreads();
    if (threadIdx.x == 0)
        out[0] = ((ws[0] + ws[1]) + (ws[2] + ws[3])) * INV_SIZE;
}

extern "C" void kernel_launch(void* const* d_in, const int* in_sizes, int n_in,
                              void* d_out, int out_size, void* d_ws, size_t ws_size,
                              hipStream_t stream) {
    const float* grid = (const float*)d_in[0];
    float* out = (float*)d_out;
    float* partials = (float*)d_ws;    // 3380 floats

    be_partials<<<dim3(NBLK), dim3(64), 0, stream>>>(grid, partials);
    be_final<<<1, 256, 0, stream>>>(partials, out);
}

// Round 11
// 155.768 us; speedup vs baseline: 1.0827x; 1.0320x over previous
//
#include <hip/hip_runtime.h>

// grid [2,160,160,160,3] fp32; interior outputs (i,j,k) in 2..157 per axis.
//
// R11 = R10 (single-wave barrier-free DPP march, 5-slice LDS ring fed by
// global_load_lds, 3-slice-deep prefetch, hand vmcnt schedule) with ONE
// change: LDS reads are a single fused inline-asm block
//     s_waitcnt vmcnt(N); 6x ds_read_b128 (offset:0..80); s_waitcnt lgkmcnt(0)
// with "=&v" outputs and NO memory clobber.
// Why: SIInsertWaitcnts models global_load_lds as an LDS-writing VMEM op and
// inserts a conservative s_waitcnt vmcnt(0) before any COMPILED ds_read that
// may alias it (it cannot prove ring slices disjoint). That drain serialized
// R10's pipeline to zero lookahead -- same stop-and-go traffic as R1-R9,
// which is why every structure pinned at ~2.3 TB/s effective read rate while
// fillBuffer proves 6.8 TB/s. Hiding the reads in asm makes the counted
// vmcnt(12) the ONLY wait; loads for slices S+1..S+3 stay in flight across
// the whole step. Schedule correctness (slice S landed at vmcnt<=12) was
// verified by R10's passing run. Consumers use the asm OUTPUTS, so data
// dependence pins them after the in-block lgkmcnt (rule #18 hazard avoided
// by construction).
#define OY 480                    // floats per y-row (160 z * 3 comps)
#define OX 76800                  // floats per x-slice
#define SB 12288000               // floats per batch
#define RST 60                    // LDS row stride (floats): 16 rows * 60 = 960
#define SLC 1024                  // ring slice stride (floats): 960 + 64 pad
#define IT 12                     // output slices (x) per wave; 13 segs
#define NSEG 13
#define NBLK 3380                 // 2(bb) * 13(jt) * 10(zt) * 13(is)
#define INV_SIZE (1.0f/22778496.0f)  // 2*156^3*3

#define ROW_SHL1 0x101
#define ROW_SHL2 0x102
#define ROW_SHR1 0x111
#define ROW_SHR2 0x112

typedef float f32x4 __attribute__((ext_vector_type(4)));

template<int CTRL>
__device__ __forceinline__ float dppf(float x){
    return __int_as_float(__builtin_amdgcn_update_dpp(
        0, __float_as_int(x), CTRL, 0xF, 0xF, true));
}

// global -> LDS direct staging, 16B per lane. LDS dest is wave-uniform base
// + lane*16 (HW rule, m104); global src is per-lane.
__device__ __forceinline__ void stage16(const float* gp, float* lp){
    __builtin_amdgcn_global_load_lds(
        (const __attribute__((address_space(1))) void*)gp,
        (__attribute__((address_space(3))) void*)lp,
        16, 0, 0);
}

// Fused wait+read block. N is a literal token. 'a' is the LDS byte address
// (VGPR). No memory clobber -> SIInsertWaitcnts adds no waits of its own;
// the vmcnt(N) inside is the only gate on the staged data.
#define LDSREAD_WAIT(N, y0,y1,y2,y3,y4,y5, a) \
    asm volatile( \
        "s_waitcnt vmcnt(" #N ")\n\t" \
        "ds_read_b128 %0, %6\n\t" \
        "ds_read_b128 %1, %6 offset:16\n\t" \
        "ds_read_b128 %2, %6 offset:32\n\t" \
        "ds_read_b128 %3, %6 offset:48\n\t" \
        "ds_read_b128 %4, %6 offset:64\n\t" \
        "ds_read_b128 %5, %6 offset:80\n\t" \
        "s_waitcnt lgkmcnt(0)" \
        : "=&v"(y0), "=&v"(y1), "=&v"(y2), "=&v"(y3), "=&v"(y4), "=&v"(y5) \
        : "v"(a))

// One x-step; S and N are LITERAL tokens. Issues slice S+3 into
// ring[(S+3)%5], then the fused block waits slice S landed and reads the
// lane's 24-float window. DPP sits under per-row-uniform qact; per-lane vr
// gates accumulation only.
#define STEPX(S, N, V0a, V0b, DP) { \
    if ((S)+3 <= 15) { \
        const float* bp = Gs + (size_t)((S)+3)*OX; \
        float* Ld = lds + (((S)+3)%5)*SLC; \
        stage16(bp+goff0, Ld); \
        stage16(bp+goff1, Ld+256); \
        stage16(bp+goff2, Ld+512); \
        stage16(bp+goff3, Ld+768); \
    } \
    if (qact) { \
        const unsigned lb = ojb + (unsigned)(((S)%5)*(SLC*4)); \
        f32x4 y0,y1,y2,y3,y4,y5; \
        LDSREAD_WAIT(N, y0,y1,y2,y3,y4,y5, lb); \
        float x[24]; \
        _Pragma("unroll") for (int q=0;q<4;++q){ \
            x[q]=y0[q]; x[4+q]=y1[q]; x[8+q]=y2[q]; \
            x[12+q]=y3[q]; x[16+q]=y4[q]; x[20+q]=y5[q]; } \
        float dz0[4],dz1[4],dz2[4],dy0[4],dy1[4],v0c[4]; \
        _Pragma("unroll") for (int v=0; v<4; ++v) { \
            v0c[v] = x[3*v+6]; \
            dz0[v] = x[3*v+9]-x[3*v+3]; dz1[v]=x[3*v+10]-x[3*v+4]; dz2[v]=x[3*v+11]-x[3*v+5]; \
            dy0[v] = dppf<ROW_SHR1>(x[3*v+6]) - dppf<ROW_SHL1>(x[3*v+6]); \
            dy1[v] = dppf<ROW_SHR1>(x[3*v+7]) - dppf<ROW_SHL1>(x[3*v+7]); \
        } \
        if ((S) >= 2 && (S) <= 13) { \
            _Pragma("unroll") for (int v=0; v<4; ++v) { \
                float c0=x[3*v+6], c1=x[3*v+7]; \
                float hy0 = dppf<ROW_SHR2>(c0) - 2.f*c0 + dppf<ROW_SHL2>(c0); \
                float hy1 = dppf<ROW_SHR2>(c1) - 2.f*c1 + dppf<ROW_SHL2>(c1); \
                float yz0 = dppf<ROW_SHR1>(dz0[v]) - dppf<ROW_SHL1>(dz0[v]); \
                float yz1 = dppf<ROW_SHR1>(dz1[v]) - dppf<ROW_SHL1>(dz1[v]); \
                float yz2 = dppf<ROW_SHR1>(dz2[v]) - dppf<ROW_SHL1>(dz2[v]); \
                if (vr) { \
                    float zz0 = x[3*v+12]-2.f*x[3*v+6]+x[3*v]; \
                    float zz1 = x[3*v+13]-2.f*x[3*v+7]+x[3*v+1]; \
                    float zz2 = x[3*v+14]-2.f*x[3*v+8]+x[3*v+2]; \
                    cls2=fmaf(zz0,zz0,cls2); cls2=fmaf(zz1,zz1,cls2); cls1=fmaf(zz2,zz2,cls1); \
                    cls2=fmaf(hy0,hy0,cls2); cls1=fmaf(hy1,hy1,cls1); \
                    cls4=fmaf(yz0,yz0,cls4); cls3=fmaf(yz1,yz1,cls3); cls1=fmaf(yz2,yz2,cls1); \
                } \
            } \
        } \
        _Pragma("unroll") for (int v=0; v<4; ++v) { \
            if (vr && (S) >= 3 && (S) <= 14) { float h; \
                h=dy0[v]-DP[0][v]; cls3=fmaf(h,h,cls3); \
                h=dy1[v]-DP[1][v]; cls1=fmaf(h,h,cls1); \
                h=dz0[v]-DP[2][v]; cls3=fmaf(h,h,cls3); \
                h=dz1[v]-DP[3][v]; cls2=fmaf(h,h,cls2); \
                h=dz2[v]-DP[4][v]; cls1=fmaf(h,h,cls1); \
            } \
            DP[0][v]=dy0[v]; DP[1][v]=dy1[v]; DP[2][v]=dz0[v]; DP[3][v]=dz1[v]; DP[4][v]=dz2[v]; \
            if (vr && (S) >= 4) { float h = v0c[v]-2.f*V0a[v]+V0b[v]; cls1=fmaf(h,h,cls1); } \
            V0b[v]=V0a[v]; V0a[v]=v0c[v]; \
        } \
    } \
}

__global__ __launch_bounds__(64)
void be_partials(const float* __restrict__ g, float* __restrict__ partial) {
    __shared__ float lds[5*SLC];   // 20 KB ring, private to this single wave

    const int tid = threadIdx.x;
    const int bid = blockIdx.x;
    const int is = bid % NSEG;
    int r1 = bid / NSEG;
    const int zt = r1 % 10; r1 /= 10;
    const int jt = r1 % 13;
    const int bb = r1 / 13;

    const int j0 = 2 + jt*12;               // output rows j0..j0+11
    const int wb = (zt < 9) ? 48*zt : 420;  // window float base (60 floats/row)
    const int i0 = 2 + is*IT;               // output slices i0..i0+11
    const float* __restrict__ Gs =
        g + (size_t)bb*SB + (size_t)(j0-2)*OY + wb + (size_t)(i0-2)*OX;

    // ---- staging addresses: 4 chunks x 64 lanes; f = 64c+lane -> row=f/15,
    // pos=f%15 (15 f4 per 60-float row). LDS float offset is implicitly 4f
    // (lane-linear) == row*60+4*pos exactly. f>=240 lanes clamp their global
    // src; their LDS bytes land in the 64-float slice pad. ----
    int goff0, goff1, goff2, goff3;
    { int f, vp;
      f = tid;       vp = f;                 goff0 = (vp/15)*OY + 4*(vp%15);
      f = tid + 64;  vp = f;                 goff1 = (vp/15)*OY + 4*(vp%15);
      f = tid + 128; vp = f;                 goff2 = (vp/15)*OY + 4*(vp%15);
      f = tid + 192; vp = (f < 240) ? f : 239; goff3 = (vp/15)*OY + 4*(vp%15); }

    // ---- compute mapping: r = y-row (DPP row pos), Q = z-quad ----
    const int r = tid & 15;
    const int Q = tid >> 4;
    const int qmax = (zt == 9) ? 3 : 4;       // zt=9 covers out z 146..157
    const bool qact = Q < qmax;               // uniform per 16-lane DPP row
    const bool vr = (r >= 2) && (r <= 13);    // output rows
    const int oj = r*RST + 12*Q + ((zt == 9) ? 12 : 0);
    const unsigned ojb = (unsigned)(uintptr_t)(lds) + 4u*(unsigned)oj;

    // x-pipeline state (parity banks A=even step, B=odd step)
    float v0A0[4],v0A1[4],v0B0[4],v0B1[4];
    float dpA[5][4], dpB[5][4];
    #pragma unroll
    for (int v=0; v<4; ++v) {
        v0A0[v]=v0A1[v]=v0B0[v]=v0B1[v]=0.f;
        #pragma unroll
        for (int q=0; q<5; ++q) { dpA[q][v]=0.f; dpB[q][v]=0.f; }
    }
    float cls1=0.f, cls2=0.f, cls3=0.f, cls4=0.f;

    // prologue: issue slices 0,1,2 into ring[0..2] (12 loads in flight)
    #pragma unroll
    for (int sl = 0; sl < 3; ++sl) {
        const float* bp = Gs + (size_t)sl*OX;
        float* Ld = lds + sl*SLC;
        stage16(bp+goff0, Ld);
        stage16(bp+goff1, Ld+256);
        stage16(bp+goff2, Ld+512);
        stage16(bp+goff3, Ld+768);
    }

    STEPX( 0, 12, v0A0,v0A1,dpA)
    STEPX( 1, 12, v0B0,v0B1,dpB)
    STEPX( 2, 12, v0A0,v0A1,dpA)
    STEPX( 3, 12, v0B0,v0B1,dpB)
    STEPX( 4, 12, v0A0,v0A1,dpA)
    STEPX( 5, 12, v0B0,v0B1,dpB)
    STEPX( 6, 12, v0A0,v0A1,dpA)
    STEPX( 7, 12, v0B0,v0B1,dpB)
    STEPX( 8, 12, v0A0,v0A1,dpA)
    STEPX( 9, 12, v0B0,v0B1,dpB)
    STEPX(10, 12, v0A0,v0A1,dpA)
    STEPX(11, 12, v0B0,v0B1,dpB)
    STEPX(12, 12, v0A0,v0A1,dpA)
    STEPX(13,  8, v0B0,v0B1,dpB)
    STEPX(14,  4, v0A0,v0A1,dpA)
    STEPX(15,  0, v0B0,v0B1,dpB)

    // fold weight classes (multiplicities 1,2,3,4; 0.0625 = (0.25)^2)
    float sv = fmaf(2.f, cls2, cls1);
    sv = fmaf(3.f, cls3, sv);
    sv = fmaf(4.f, cls4, sv);
    sv *= 0.0625f;

    #pragma unroll
    for (int off = 32; off > 0; off >>= 1) sv += __shfl_down(sv, off, 64);
    if (tid == 0) partial[bid] = sv;
}

__global__ __launch_bounds__(256)
void be_final(const float* __restrict__ partial, float* __restrict__ out) {
    float s = 0.0f;
    for (int i = threadIdx.x; i < NBLK; i += 256) s += partial[i];
    #pragma unroll
    for (int off = 32; off > 0; off >>= 1) s += __shfl_down(s, off, 64);
    __shared__ float ws[4];
    if ((threadIdx.x & 63) == 0) ws[threadIdx.x >> 6] = s;
    __syncthreads();
    if (threadIdx.x == 0)
        out[0] = ((ws[0] + ws[1]) + (ws[2] + ws[3])) * INV_SIZE;
}

extern "C" void kernel_launch(void* const* d_in, const int* in_sizes, int n_in,
                              void* d_out, int out_size, void* d_ws, size_t ws_size,
                              hipStream_t stream) {
    const float* grid = (const float*)d_in[0];
    float* out = (float*)d_out;
    float* partials = (float*)d_ws;    // 3380 floats

    be_partials<<<dim3(NBLK), dim3(64), 0, stream>>>(grid, partials);
    be_final<<<1, 256, 0, stream>>>(partials, out);
}